// Round 6
// baseline (1378.820 us; speedup 1.0000x reference)
//
#include <hip/hip_runtime.h>
#include <cstdint>
#include <cstddef>

// SAMGuidedCrossAttention: B=4, C=256, H=W=256, heads=8, ws=8, d=32
//   prep_weights: wq/wk/wv/wp f32 -> bf16 in MFMA-FRAGMENT ORDER
//   qkv_gemm v6: 512-thr 2-PHASE PIPELINE, register-budgeted (no spill):
//     stage regs 8xfloat4 = 32 VGPR (512 thr), acc[4][2]=32, A-frags 4.
//     Wave (ow=wid&3, nh=wid>>2): M=64 rows x N=32 cols.
//     Double-buffered 2x32KB LDS stage; issue(t+1) at tile top, pack->alt
//     after the K (or Q) pass; 1 barrier/tile Q, 2 KV. 2 blocks/CU.
//     Q-block = 2 image rows (8 tiles); KV-block = 1 row (4 tiles, K+V from
//     one xkv stage). V transpose wave-local in dead cur buffer (g-XOR swz).
//   attn_conv: unchanged (proven; XCD-chunked winl swizzle, wpT frags).

typedef __attribute__((ext_vector_type(8))) short bfx8;   // 8 bf16 (4 VGPR)
typedef __attribute__((ext_vector_type(4))) float f32x4;  // MFMA acc

#define HW 65536
#define NC 256
#define QKV_STRIDE 16777216UL  // ushorts per tensor per batch (1024*8*64*32)

__device__ __forceinline__ unsigned short f2bf(float f) {
  union { float f; unsigned u; } v; v.f = f;
  unsigned r = v.u + 0x7FFFu + ((v.u >> 16) & 1u);  // RNE
  return (unsigned short)(r >> 16);
}

// row-dependent XOR swizzle for the staged X tile (bits 4-6 of byte addr)
__device__ __forceinline__ unsigned xswz(unsigned n) {
  return ((n ^ (n >> 2)) & 7u) << 4;
}

// weights -> MFMA fragment order. dst[i]: i = ((o_tile*8+ks)*64+lane)*8+e
// holds w[o_tile*16 + (lane&15)][ks*32 + (lane>>4)*8 + e].
__global__ __launch_bounds__(256) void prep_weights(
    const float* __restrict__ wq, const float* __restrict__ wk,
    const float* __restrict__ wv, const float* __restrict__ wp,
    unsigned short* __restrict__ dst) {
  int i = blockIdx.x * 256 + threadIdx.x;  // grid 256 x 256 (65536 elements)
  int e = i & 7, lane = (i >> 3) & 63, ks = (i >> 9) & 7, ot = i >> 12;
  int src = (ot * 16 + (lane & 15)) * 256 + ks * 32 + (lane >> 4) * 8 + e;
  dst[i]          = f2bf(wq[src]);
  dst[i + 65536]  = f2bf(wk[src]);
  dst[i + 131072] = f2bf(wv[src]);
  dst[i + 196608] = f2bf(wp[src]);
}

// GEMM pass for 8-wave blocks: wave = M 64 rows (ow) x N 32 cols (nh).
__device__ __forceinline__ void gemm_pass8(
    const unsigned short* __restrict__ wT, const unsigned char* __restrict__ smem,
    int ow, int nh, int g, int qh, int lane, f32x4 (&acc)[4][2]) {
#pragma unroll
  for (int i = 0; i < 4; ++i) {
    acc[i][0] = (f32x4){0.f, 0.f, 0.f, 0.f};
    acc[i][1] = (f32x4){0.f, 0.f, 0.f, 0.f};
  }
  bfx8 afr[4];
#pragma unroll
  for (int mt = 0; mt < 4; ++mt)
    afr[mt] = *(const bfx8*)(wT + (((ow * 4 + mt) * 8 + 0) * 64 + lane) * 8);

  for (int ks = 0; ks < 8; ++ks) {
    bfx8 naf[4];
    if (ks < 7) {
#pragma unroll
      for (int mt = 0; mt < 4; ++mt)
        naf[mt] = *(const bfx8*)(wT + (((ow * 4 + mt) * 8 + ks + 1) * 64 + lane) * 8);
    }
#pragma unroll
    for (int nt = 0; nt < 2; ++nt) {
      unsigned n = (unsigned)(nh * 32 + nt * 16 + qh);
      bfx8 bfr = *(const bfx8*)(smem + ((n * 512 + (unsigned)(ks * 64 + g * 16)) ^ xswz(n)));
#pragma unroll
      for (int mt = 0; mt < 4; ++mt)
        acc[mt][nt] = __builtin_amdgcn_mfma_f32_16x16x32_bf16(afr[mt], bfr, acc[mt][nt], 0, 0, 0);
    }
    if (ks < 7) {
#pragma unroll
      for (int mt = 0; mt < 4; ++mt) afr[mt] = naf[mt];
    }
  }
}

// Direct windowed store for Q/K layout [win*8+head][pos 64][d 32] (+bias).
__device__ __forceinline__ void store_qk8(
    const f32x4 (&acc)[4][2], const float* __restrict__ bias,
    unsigned short* __restrict__ outw, int row, int w0b,
    int ow, int nh, int g, int qh) {
#pragma unroll
  for (int mt = 0; mt < 4; ++mt) {
    int o = ow * 64 + mt * 16 + g * 4;
    f32x4 bb = *(const f32x4*)&bias[o];
    int head = o >> 5, dbase = o & 31;
#pragma unroll
    for (int nt = 0; nt < 2; ++nt) {
      int pidx = nh * 32 + nt * 16 + qh;
      int w_img = w0b + pidx;
      int win = ((row >> 3) << 5) + (w_img >> 3);
      int pos = ((row & 7) << 3) + (w_img & 7);
      f32x4 a = acc[mt][nt];
      uint2 pv;
      pv.x = (unsigned)f2bf(a.x + bb.x) | ((unsigned)f2bf(a.y + bb.y) << 16);
      pv.y = (unsigned)f2bf(a.z + bb.z) | ((unsigned)f2bf(a.w + bb.w) << 16);
      *(uint2*)&outw[((size_t)(win * 8 + head) * 64 + pos) * 32 + dbase] = pv;
    }
  }
}

// ---------------- QKV projection GEMM (2-phase pipelined) ----------------
// grid (384, 1, NB), 512 thr (8 waves). idx<128: Q-block (2 rows, 8 tiles);
// idx>=128: KV-block (1 row, 4 tiles, K+V from one xkv stage).
__global__ __launch_bounds__(512, 4) void qkv_gemm(
    const float* __restrict__ xq, const float* __restrict__ xkv,
    const unsigned short* __restrict__ wbf,
    const float* __restrict__ bq, const float* __restrict__ bk,
    const float* __restrict__ bv,
    unsigned short* __restrict__ q_w, unsigned short* __restrict__ k_w,
    unsigned short* __restrict__ v_w, int batch0, int batched) {
  __shared__ __align__(16) unsigned char smem[2][32768];  // double-buffered stage

  const int tid = threadIdx.x;
  const int lane = tid & 63;
  const int wid = tid >> 6;        // 0..7
  const int g = lane >> 4;
  const int qh = lane & 15;
  const int ow = wid & 3;          // M-slice (64 rows)
  const int nh = wid >> 2;         // N-half (32 cols)

  const int idx = blockIdx.x;
  const int batch = batch0 + blockIdx.z;
  const size_t qofs = batched ? (size_t)blockIdx.z * QKV_STRIDE : 0;
  const bool isQ = idx < 128;
  const int nT = isQ ? 8 : 4;
  const float* x = (isQ ? xq : xkv) + (size_t)batch * NC * HW;

  // staging map: 16 threads -> pos quads, 32 channel-octets
  const int n4 = tid & 15;
  const int cgrp = tid >> 4;       // 0..31
  const float* xb = x + (size_t)(cgrp * 8) * HW + n4 * 4;

  f32x4 ld[8];  // in-flight x tile slice (32 VGPR)
  auto n0_of = [&](int t) {
    return isQ ? ((idx * 2 + (t >> 2)) * 256 + (t & 3) * 64)
               : ((idx - 128) * 256 + t * 64);
  };
  auto issue = [&](int t) {
    const int n0 = n0_of(t);
#pragma unroll
    for (int i = 0; i < 8; ++i) ld[i] = *(const f32x4*)(xb + (size_t)i * HW + n0);
  };
  auto pack = [&](unsigned char* dst) {
#pragma unroll
    for (int e = 0; e < 4; ++e) {
      unsigned n = (unsigned)(n4 * 4 + e);
      uint4 u;
      u.x = (unsigned)f2bf(ld[0][e]) | ((unsigned)f2bf(ld[1][e]) << 16);
      u.y = (unsigned)f2bf(ld[2][e]) | ((unsigned)f2bf(ld[3][e]) << 16);
      u.z = (unsigned)f2bf(ld[4][e]) | ((unsigned)f2bf(ld[5][e]) << 16);
      u.w = (unsigned)f2bf(ld[6][e]) | ((unsigned)f2bf(ld[7][e]) << 16);
      *(uint4*)(dst + ((n * 512 + (unsigned)cgrp * 16) ^ xswz(n))) = u;
    }
  };

  issue(0);
  pack(smem[0]);

  for (int t = 0; t < nT; ++t) {
    unsigned char* cur = smem[t & 1];
    unsigned char* alt = smem[(t + 1) & 1];
    __syncthreads();               // cur packed+visible; alt reads (t-1) done
    if (t + 1 < nT) issue(t + 1);  // next tile's loads fly under this GEMM
    const int n0 = n0_of(t);
    const int row = n0 >> 8, w0b = n0 & 255;

    if (isQ) {
      f32x4 acc[4][2];
      gemm_pass8(wbf, cur, ow, nh, g, qh, lane, acc);
      store_qk8(acc, bq, q_w + qofs, row, w0b, ow, nh, g, qh);
      if (t + 1 < nT) pack(alt);
    } else {
      f32x4 acc[4][2];
      gemm_pass8(wbf + 65536, cur, ow, nh, g, qh, lane, acc);      // wk
      store_qk8(acc, bk, k_w + qofs, row, w0b, ow, nh, g, qh);
      if (t + 1 < nT) pack(alt);   // ld dies here; V-pass runs reg-light
      f32x4 vacc[4][2];
      gemm_pass8(wbf + 131072, cur, ow, nh, g, qh, lane, vacc);    // wv
      __syncthreads();             // all cur reads done -> wave-local V-epi in cur
      char* vb_ = (char*)cur + wid * 4096;  // [64 loc][32 n] x 8 waves
#pragma unroll
      for (int mt = 0; mt < 4; ++mt) {
        int o = ow * 64 + mt * 16 + g * 4;
        f32x4 bb = *(const f32x4*)&bv[o];
        int loc0 = mt * 16 + g * 4;
        unsigned sw = (unsigned)g << 4;  // == ((loc>>2)&3)<<4 for these rows
#pragma unroll
        for (int nt = 0; nt < 2; ++nt) {
          int nl = nt * 16 + qh;
          f32x4 a = vacc[mt][nt];
          *(unsigned short*)(vb_ + ((unsigned)((loc0 + 0) * 64 + nl * 2) ^ sw)) = f2bf(a.x + bb.x);
          *(unsigned short*)(vb_ + ((unsigned)((loc0 + 1) * 64 + nl * 2) ^ sw)) = f2bf(a.y + bb.y);
          *(unsigned short*)(vb_ + ((unsigned)((loc0 + 2) * 64 + nl * 2) ^ sw)) = f2bf(a.z + bb.z);
          *(unsigned short*)(vb_ + ((unsigned)((loc0 + 3) * 64 + nl * 2) ^ sw)) = f2bf(a.w + bb.w);
        }
      }
      {
        int head = ow * 2 + (lane >> 5), dd = lane & 31;
        unsigned rsw = (unsigned)((lane >> 2) & 3) << 4;
        unsigned short* vw = v_w + qofs;
#pragma unroll
        for (int c = 0; c < 4; ++c) {
          uint4 val = *(const uint4*)(vb_ + ((unsigned)(lane * 64 + c * 16) ^ rsw));
          int w_img = w0b + nh * 32 + c * 8;
          int win = ((row >> 3) << 5) + (w_img >> 3);
          *(uint4*)&vw[((size_t)(win * 8 + head) * 32 + dd) * 64 + ((row & 7) << 3)] = val;
        }
      }
    }
  }
}

// ---------------- fused windowed attention + output conv ----------------
// Block: 256 thr (4 waves) = 1 window. Wave handles heads {wid, wid+4}.
__global__ __launch_bounds__(256) void attn_conv(
    const unsigned short* __restrict__ q_w, const unsigned short* __restrict__ k_w,
    const unsigned short* __restrict__ v_w, const unsigned short* __restrict__ wpT,
    const float* __restrict__ bp, float* __restrict__ out, int batch0, int batched) {
  __shared__ unsigned short P_lds[4][2048];  // per-wave P half-tile [64 q][32 k], swizzled
  __shared__ unsigned short y_t[16384];      // [pos 64][c 256] bf16, swizzled

  const int tid = threadIdx.x;
  const int lane = tid & 63;
  const int wid = tid >> 6;
  const int g = lane >> 4;
  const int qh = lane & 15;
  const int bid = blockIdx.x;
  // XCD-chunked swizzle: XCD j owns winl [j*128, +128).
  const int winl = ((bid & 7) << 7) | (bid >> 3);
  const int batch = batch0 + blockIdx.z;
  const size_t qofs = batched ? (size_t)blockIdx.z * QKV_STRIDE : 0;
  const float scale = 0.17677669529663687f;  // 1/sqrt(32)

  char* pbase = (char*)&P_lds[wid][0];

#pragma unroll
  for (int hi = 0; hi < 2; ++hi) {
    const int head = wid + hi * 4;
    const unsigned short* qb = q_w + qofs + (size_t)(winl * 8 + head) * 2048;
    const unsigned short* kb = k_w + qofs + (size_t)(winl * 8 + head) * 2048;
    const unsigned short* vb = v_w + qofs + (size_t)(winl * 8 + head) * 2048;

    bfx8 kf[4], qf[4];
#pragma unroll
    for (int t = 0; t < 4; ++t) {
      kf[t] = *(const bfx8*)(kb + (t * 16 + qh) * 32 + g * 8);
      qf[t] = *(const bfx8*)(qb + (t * 16 + qh) * 32 + g * 8);
    }
    // S^T[kpos][q] = sum_d K[kpos][d] * Q[q][d]
    f32x4 zero = {0.f, 0.f, 0.f, 0.f};
    f32x4 st[4][4];
#pragma unroll
    for (int kt = 0; kt < 4; ++kt)
#pragma unroll
      for (int qt = 0; qt < 4; ++qt)
        st[kt][qt] = __builtin_amdgcn_mfma_f32_16x16x32_bf16(kf[kt], qf[qt], zero, 0, 0, 0);

    // softmax over kpos (rows of S^T)
    float rv[4];
#pragma unroll
    for (int qt = 0; qt < 4; ++qt) {
      float m = -1e30f;
#pragma unroll
      for (int kt = 0; kt < 4; ++kt) {
        f32x4 v = st[kt][qt];
        m = fmaxf(m, fmaxf(fmaxf(v.x, v.y), fmaxf(v.z, v.w)));
      }
      m = fmaxf(m, __shfl_xor(m, 16, 64));
      m = fmaxf(m, __shfl_xor(m, 32, 64));
      float ssum = 0.f;
#pragma unroll
      for (int kt = 0; kt < 4; ++kt) {
        f32x4 v = st[kt][qt], e;
        e.x = __expf((v.x - m) * scale);
        e.y = __expf((v.y - m) * scale);
        e.z = __expf((v.z - m) * scale);
        e.w = __expf((v.w - m) * scale);
        ssum += e.x + e.y + e.z + e.w;
        st[kt][qt] = e;
      }
      ssum += __shfl_xor(ssum, 16, 64);
      ssum += __shfl_xor(ssum, 32, 64);
      rv[qt] = 1.f / ssum;
    }

    // PV: out^T[d][q] = sum_k V^T[d][k] * P
    f32x4 ot[2][4];
#pragma unroll
    for (int dt = 0; dt < 2; ++dt)
#pragma unroll
      for (int qt = 0; qt < 4; ++qt) ot[dt][qt] = zero;

#pragma unroll
    for (int s = 0; s < 2; ++s) {
#pragma unroll
      for (int qt = 0; qt < 4; ++qt) {
        int q = qt * 16 + qh;
        unsigned sw = ((unsigned)(q & 3)) << 4;
        float r = rv[qt];
#pragma unroll
        for (int k2 = 0; k2 < 2; ++k2) {
          f32x4 e = st[s * 2 + k2][qt];
          uint2 pv;
          pv.x = (unsigned)f2bf(e.x * r) | ((unsigned)f2bf(e.y * r) << 16);
          pv.y = (unsigned)f2bf(e.z * r) | ((unsigned)f2bf(e.w * r) << 16);
          unsigned byte = ((unsigned)q * 64 + (unsigned)(k2 * 32 + g * 8)) ^ sw;
          *(uint2*)(pbase + byte) = pv;
        }
      }
      bfx8 pf[4];
#pragma unroll
      for (int qt = 0; qt < 4; ++qt) {
        int q = qt * 16 + qh;
        unsigned byte = ((unsigned)q * 64 + (unsigned)(g * 16)) ^ (((unsigned)(q & 3)) << 4);
        pf[qt] = *(const bfx8*)(pbase + byte);
      }
#pragma unroll
      for (int dt = 0; dt < 2; ++dt) {
        bfx8 vf = *(const bfx8*)(vb + (dt * 16 + qh) * 64 + s * 32 + g * 8);
#pragma unroll
        for (int qt = 0; qt < 4; ++qt)
          ot[dt][qt] = __builtin_amdgcn_mfma_f32_16x16x32_bf16(vf, pf[qt], ot[dt][qt], 0, 0, 0);
      }
    }

    // attention output -> y_t[pos][c] (swizzled), c = head*32 + d
#pragma unroll
    for (int dt = 0; dt < 2; ++dt) {
      int cb = head * 32 + dt * 16 + g * 4;
#pragma unroll
      for (int qt = 0; qt < 4; ++qt) {
        int pos = qt * 16 + qh;
        f32x4 a = ot[dt][qt];
        uint2 pv;
        pv.x = (unsigned)f2bf(a.x) | ((unsigned)f2bf(a.y) << 16);
        pv.y = (unsigned)f2bf(a.z) | ((unsigned)f2bf(a.w) << 16);
        unsigned byte = ((unsigned)pos * 512 + (unsigned)cb * 2) ^ (((unsigned)(pos & 7)) << 4);
        *(uint2*)((char*)y_t + byte) = pv;
      }
    }
  }
  __syncthreads();

  // output conv: out[o][pos] = sum_c wp[o][c] * y[c][pos]; wave wid: o in [64*wid, +64)
  f32x4 acc[4][4];
#pragma unroll
  for (int i = 0; i < 4; ++i)
#pragma unroll
    for (int j = 0; j < 4; ++j) acc[i][j] = (f32x4){0.f, 0.f, 0.f, 0.f};

  for (int ks = 0; ks < 8; ++ks) {
    bfx8 af[4];
#pragma unroll
    for (int mt = 0; mt < 4; ++mt)
      af[mt] = *(const bfx8*)(wpT + (((wid * 4 + mt) * 8 + ks) * 64 + lane) * 8);
#pragma unroll
    for (int nt = 0; nt < 4; ++nt) {
      int pos = nt * 16 + qh;
      unsigned byte = ((unsigned)pos * 512 + (unsigned)(ks * 64 + g * 16)) ^ (((unsigned)(pos & 7)) << 4);
      bfx8 bfr = *(const bfx8*)((char*)y_t + byte);
#pragma unroll
      for (int mt = 0; mt < 4; ++mt)
        acc[mt][nt] = __builtin_amdgcn_mfma_f32_16x16x32_bf16(af[mt], bfr, acc[mt][nt], 0, 0, 0);
    }
  }

  const int wrow = winl >> 5, wcol = winl & 31;
  float* ob_ = out + (size_t)batch * NC * HW;
#pragma unroll
  for (int mt = 0; mt < 4; ++mt) {
    int o0 = wid * 64 + mt * 16 + g * 4;
    float b0 = bp[o0], b1 = bp[o0 + 1], b2 = bp[o0 + 2], b3 = bp[o0 + 3];
#pragma unroll
    for (int nt = 0; nt < 4; ++nt) {
      int pos = nt * 16 + qh;
      int h_img = wrow * 8 + (pos >> 3);
      int w_img = wcol * 8 + (pos & 7);
      float* pp = ob_ + (size_t)o0 * HW + h_img * 256 + w_img;
      pp[0]      = acc[mt][nt].x + b0;
      pp[HW]     = acc[mt][nt].y + b1;
      pp[2 * HW] = acc[mt][nt].z + b2;
      pp[3 * HW] = acc[mt][nt].w + b3;
    }
  }
}

extern "C" void kernel_launch(void* const* d_in, const int* in_sizes, int n_in,
                              void* d_out, int out_size, void* d_ws, size_t ws_size,
                              hipStream_t stream) {
  const float* q_feat = (const float*)d_in[0];
  const float* kv_feat = (const float*)d_in[1];
  const float* wq = (const float*)d_in[2];
  const float* bq = (const float*)d_in[3];
  const float* wk = (const float*)d_in[4];
  const float* bk = (const float*)d_in[5];
  const float* wv = (const float*)d_in[6];
  const float* bv = (const float*)d_in[7];
  const float* wp = (const float*)d_in[8];
  const float* bp = (const float*)d_in[9];
  float* out = (float*)d_out;

  unsigned short* wbf = (unsigned short*)d_ws;  // 4 x 65536 bf16 = 512 KB
  const size_t need_batched = 524288ul + 12ul * QKV_STRIDE * 2ul;  // ~403 MB

  hipLaunchKernelGGL(prep_weights, dim3(256), dim3(256), 0, stream, wq, wk, wv, wp, wbf);

  if (ws_size >= need_batched) {
    // all-batch path: 2 big launches, no inter-batch serialization bubbles
    unsigned short* q_w = wbf + 262144;
    unsigned short* k_w = q_w + 4 * QKV_STRIDE;
    unsigned short* v_w = k_w + 4 * QKV_STRIDE;
    hipLaunchKernelGGL(qkv_gemm, dim3(384, 1, 4), dim3(512), 0, stream,
                       q_feat, kv_feat, wbf, bq, bk, bv, q_w, k_w, v_w, 0, 1);
    hipLaunchKernelGGL(attn_conv, dim3(1024, 1, 4), dim3(256), 0, stream,
                       q_w, k_w, v_w, wbf + 196608, bp, out, 0, 1);
  } else {
    // per-batch fallback (~97 MB workspace)
    unsigned short* q_w = wbf + 262144;
    unsigned short* k_w = q_w + QKV_STRIDE;
    unsigned short* v_w = k_w + QKV_STRIDE;
    for (int b = 0; b < 4; ++b) {
      hipLaunchKernelGGL(qkv_gemm, dim3(384, 1, 1), dim3(512), 0, stream,
                         q_feat, kv_feat, wbf, bq, bk, bv, q_w, k_w, v_w, b, 0);
      hipLaunchKernelGGL(attn_conv, dim3(1024, 1, 1), dim3(256), 0, stream,
                         q_w, k_w, v_w, wbf + 196608, bp, out, b, 0);
    }
  }
}

// Round 7
// 732.106 us; speedup vs baseline: 1.8834x; 1.8834x over previous
//
#include <hip/hip_runtime.h>
#include <cstdint>
#include <cstddef>

// SAMGuidedCrossAttention: B=4, C=256, H=W=256, heads=8, ws=8, d=32
// ROUND 7: revert qkv to the proven round-2 kernel (457us, no spill) and add
// two DIAGNOSTIC dispatches (batch-0 grid only, outputs to ws scratch) to
// empirically split qkv time into stage / gemm / store phases:
//   qkv_stage_diag   : x load + bf16 pack + LDS + barrier only
//   qkv_nostore_diag : + full GEMM passes (acc folded to 1 scalar store)
//   qkv_gemm (real)  : full round-2 kernel -> correct outputs
// 5 dispatches total -> all visible in rocprof top-5 with counters.
//   prep_weights: wq/wk/wv ROW order (round-2 qkv layout) + wp FRAGMENT order
//   attn_conv: proven kernel (XCD-chunked winl swizzle, wpT fragment loads).

typedef __attribute__((ext_vector_type(8))) short bfx8;   // 8 bf16 (4 VGPR)
typedef __attribute__((ext_vector_type(4))) float f32x4;  // MFMA acc

#define HW 65536
#define NC 256
#define QKV_STRIDE 16777216UL  // ushorts per tensor per batch (1024*8*64*32)

__device__ __forceinline__ unsigned short f2bf(float f) {
  union { float f; unsigned u; } v; v.f = f;
  unsigned r = v.u + 0x7FFFu + ((v.u >> 16) & 1u);  // RNE
  return (unsigned short)(r >> 16);
}

// wq/wk/wv: plain row-order bf16 copy. wp: MFMA fragment order for attn_conv.
__global__ __launch_bounds__(256) void prep_weights(
    const float* __restrict__ wq, const float* __restrict__ wk,
    const float* __restrict__ wv, const float* __restrict__ wp,
    unsigned short* __restrict__ dst) {
  int i = blockIdx.x * 256 + threadIdx.x;  // 65536 elements
  dst[i]          = f2bf(wq[i]);
  dst[i + 65536]  = f2bf(wk[i]);
  dst[i + 131072] = f2bf(wv[i]);
  int e = i & 7, lane = (i >> 3) & 63, ks = (i >> 9) & 7, ot = i >> 12;
  int src = (ot * 16 + (lane & 15)) * 256 + ks * 32 + (lane >> 4) * 8 + e;
  dst[i + 196608] = f2bf(wp[src]);
}

// ---- round-2 staging: X[256 c][n0..n0+64) -> Xs[n][c] bf16, swz ((n&7)<<4)
__device__ __forceinline__ void stage_x(
    const float* __restrict__ x, int n0, int tid, unsigned char* __restrict__ smem) {
  const int sn = tid & 63;   // lane -> contiguous n (coalesced 256B/row)
  const int oc = tid >> 6;
#pragma unroll
  for (int it = 0; it < 8; ++it) {
    int c8 = (it * 4 + oc) * 8;
    const float* xp = x + (size_t)c8 * HW + n0 + sn;
    float v0 = xp[0],      v1 = xp[HW],     v2 = xp[2 * HW], v3 = xp[3 * HW];
    float v4 = xp[4 * HW], v5 = xp[5 * HW], v6 = xp[6 * HW], v7 = xp[7 * HW];
    uint4 u;
    u.x = (unsigned)f2bf(v0) | ((unsigned)f2bf(v1) << 16);
    u.y = (unsigned)f2bf(v2) | ((unsigned)f2bf(v3) << 16);
    u.z = (unsigned)f2bf(v4) | ((unsigned)f2bf(v5) << 16);
    u.w = (unsigned)f2bf(v6) | ((unsigned)f2bf(v7) << 16);
    unsigned byte = ((unsigned)(sn * 512 + c8 * 2)) ^ (((unsigned)(sn & 7)) << 4);
    *(uint4*)(smem + byte) = u;  // 16B write, conflict-free
  }
}

// round-2 GEMM pass: acc = W[256x256] * Xs. W row-order; Xs as staged above.
__device__ __forceinline__ void gemm_pass(
    const unsigned short* __restrict__ wmat, const unsigned char* __restrict__ smem,
    int wid, int g, int qh, f32x4 (&acc)[4][4]) {
#pragma unroll
  for (int i = 0; i < 4; ++i)
#pragma unroll
    for (int j = 0; j < 4; ++j) acc[i][j] = (f32x4){0.f, 0.f, 0.f, 0.f};

  bfx8 afr[4];
#pragma unroll
  for (int mt = 0; mt < 4; ++mt)
    afr[mt] = *(const bfx8*)(wmat + (wid * 64 + mt * 16 + qh) * 256 + g * 8);

  for (int ks = 0; ks < 8; ++ks) {
    bfx8 naf[4];
    if (ks < 7) {
#pragma unroll
      for (int mt = 0; mt < 4; ++mt)
        naf[mt] = *(const bfx8*)(wmat + (wid * 64 + mt * 16 + qh) * 256 + (ks + 1) * 32 + g * 8);
    }
#pragma unroll
    for (int nt = 0; nt < 4; ++nt) {
      unsigned byte = ((unsigned)((nt * 16 + qh) * 512 + ks * 64 + g * 16)) ^
                      (((unsigned)(qh & 7)) << 4);
      bfx8 bfr = *(const bfx8*)(smem + byte);
#pragma unroll
      for (int mt = 0; mt < 4; ++mt)
        acc[mt][nt] = __builtin_amdgcn_mfma_f32_16x16x32_bf16(afr[mt], bfr, acc[mt][nt], 0, 0, 0);
    }
    if (ks < 7) {
#pragma unroll
      for (int mt = 0; mt < 4; ++mt) afr[mt] = naf[mt];
    }
  }
}

// Direct windowed store for Q/K layout [win*8+head][pos 64][d 32] (+bias).
__device__ __forceinline__ void store_qk(
    const f32x4 (&acc)[4][4], const float* __restrict__ bias,
    unsigned short* __restrict__ outw, int n0, int wid, int g, int qh) {
  const int h_img = n0 >> 8, w0b = n0 & 255;
#pragma unroll
  for (int mt = 0; mt < 4; ++mt) {
    int o = wid * 64 + mt * 16 + g * 4;
    f32x4 bb = *(const f32x4*)&bias[o];
    int head = o >> 5, dbase = o & 31;
#pragma unroll
    for (int nt = 0; nt < 4; ++nt) {
      int n = nt * 16 + qh;
      int w_img = w0b + n;
      int win = ((h_img >> 3) << 5) + (w_img >> 3);
      int pos = ((h_img & 7) << 3) + (w_img & 7);
      f32x4 a = acc[mt][nt];
      uint2 pv;
      pv.x = (unsigned)f2bf(a.x + bb.x) | ((unsigned)f2bf(a.y + bb.y) << 16);
      pv.y = (unsigned)f2bf(a.z + bb.z) | ((unsigned)f2bf(a.w + bb.w) << 16);
      *(uint2*)&outw[((size_t)(win * 8 + head) * 64 + pos) * 32 + dbase] = pv;
    }
  }
}

// ---------------- DIAGNOSTIC: staging only ----------------
__global__ __launch_bounds__(256) void qkv_stage_diag(
    const float* __restrict__ xq, const float* __restrict__ xkv,
    float* __restrict__ scratch) {
  __shared__ __align__(16) unsigned char smem[32768];
  const int tid = threadIdx.x;
  const int mode = blockIdx.x & 1;
  const int n0 = (int)(blockIdx.x >> 1) * 64;
  const float* x = mode ? xkv : xq;  // batch 0
  stage_x(x, n0, tid, smem);
  __syncthreads();
  unsigned v = *(const unsigned*)(smem + tid * 128);  // keep pack live
  scratch[blockIdx.x * 256 + tid] = (float)v;
}

// ---------------- DIAGNOSTIC: staging + GEMM, no windowed store ----------------
__global__ __launch_bounds__(256) void qkv_nostore_diag(
    const float* __restrict__ xq, const float* __restrict__ xkv,
    const unsigned short* __restrict__ wbf, float* __restrict__ scratch) {
  __shared__ __align__(16) unsigned char smem[32768];
  const int tid = threadIdx.x;
  const int lane = tid & 63;
  const int wid = tid >> 6;
  const int g = lane >> 4;
  const int qh = lane & 15;
  const int mode = blockIdx.x & 1;
  const int n0 = (int)(blockIdx.x >> 1) * 64;
  const float* x = mode ? xkv : xq;  // batch 0
  stage_x(x, n0, tid, smem);
  __syncthreads();
  float s = 0.f;
  f32x4 acc[4][4];
  if (mode == 0) {
    gemm_pass(wbf, smem, wid, g, qh, acc);
#pragma unroll
    for (int i = 0; i < 4; ++i)
#pragma unroll
      for (int j = 0; j < 4; ++j) s += acc[i][j].x + acc[i][j].y + acc[i][j].z + acc[i][j].w;
  } else {
    gemm_pass(wbf + 65536, smem, wid, g, qh, acc);
#pragma unroll
    for (int i = 0; i < 4; ++i)
#pragma unroll
      for (int j = 0; j < 4; ++j) s += acc[i][j].x + acc[i][j].y + acc[i][j].z + acc[i][j].w;
    gemm_pass(wbf + 131072, smem, wid, g, qh, acc);
#pragma unroll
    for (int i = 0; i < 4; ++i)
#pragma unroll
      for (int j = 0; j < 4; ++j) s += acc[i][j].x + acc[i][j].y + acc[i][j].z + acc[i][j].w;
  }
  scratch[blockIdx.x * 256 + tid] = s;  // keep MFMAs live
}

// ---------------- QKV projection GEMM (round-2 exact) ----------------
// grid (2048, 1, NB), 256 thr (4 waves). bid&1: 0 = Q, 1 = K+V (shared stage).
__global__ __launch_bounds__(256) void qkv_gemm(
    const float* __restrict__ xq, const float* __restrict__ xkv,
    const unsigned short* __restrict__ wbf,
    const float* __restrict__ bq, const float* __restrict__ bk,
    const float* __restrict__ bv,
    unsigned short* __restrict__ q_w, unsigned short* __restrict__ k_w,
    unsigned short* __restrict__ v_w, int batch0, int batched) {
  __shared__ __align__(16) unsigned char smem[36864];  // stage 32KB | V-epi 36KB

  const int tid = threadIdx.x;
  const int lane = tid & 63;
  const int wid = tid >> 6;
  const int g = lane >> 4;
  const int qh = lane & 15;
  const int mode = blockIdx.x & 1;
  const int n0 = (int)(blockIdx.x >> 1) * 64;
  const int batch = batch0 + blockIdx.z;
  const size_t qofs = batched ? (size_t)blockIdx.z * QKV_STRIDE : 0;
  const float* x = (mode ? xkv : xq) + (size_t)batch * NC * HW;

  stage_x(x, n0, tid, smem);
  __syncthreads();  // the ONLY barrier before the MFMA stream

  f32x4 acc[4][4];
  if (mode == 0) {
    gemm_pass(wbf, smem, wid, g, qh, acc);                 // wq
    store_qk(acc, bq, q_w + qofs, n0, wid, g, qh);
  } else {
    gemm_pass(wbf + 65536, smem, wid, g, qh, acc);         // wk
    store_qk(acc, bk, k_w + qofs, n0, wid, g, qh);
    gemm_pass(wbf + 131072, smem, wid, g, qh, acc);        // wv (stage reused)
    __syncthreads();  // all stage reads done -> alias V-epi over stage
    unsigned short* Vt = (unsigned short*)smem;            // [o 256][n 64 pad 72]
#pragma unroll
    for (int mt = 0; mt < 4; ++mt) {
      int o = wid * 64 + mt * 16 + g * 4;
      f32x4 bb = *(const f32x4*)&bv[o];
#pragma unroll
      for (int nt = 0; nt < 4; ++nt) {
        int n = nt * 16 + qh;
        f32x4 a = acc[mt][nt];
        Vt[(o + 0) * 72 + n] = f2bf(a.x + bb.x);
        Vt[(o + 1) * 72 + n] = f2bf(a.y + bb.y);
        Vt[(o + 2) * 72 + n] = f2bf(a.z + bb.z);
        Vt[(o + 3) * 72 + n] = f2bf(a.w + bb.w);
      }
    }
    __syncthreads();
    const int h_img = n0 >> 8, w0b = n0 & 255;
    unsigned short* vw = v_w + qofs;
#pragma unroll
    for (int it = 0; it < 8; ++it) {
      int id = it * 256 + tid;
      int o = id >> 3, oct = id & 7;
      uint4 val = *(const uint4*)&Vt[o * 72 + oct * 8];
      int head = o >> 5, dd = o & 31;
      int win = ((h_img >> 3) << 5) + (w0b >> 3) + oct;
      *(uint4*)&vw[((size_t)(win * 8 + head) * 32 + dd) * 64 + ((h_img & 7) << 3)] = val;
    }
  }
}

// ---------------- fused windowed attention + output conv ----------------
// Block: 256 thr (4 waves) = 1 window. Wave handles heads {wid, wid+4}.
__global__ __launch_bounds__(256) void attn_conv(
    const unsigned short* __restrict__ q_w, const unsigned short* __restrict__ k_w,
    const unsigned short* __restrict__ v_w, const unsigned short* __restrict__ wpT,
    const float* __restrict__ bp, float* __restrict__ out, int batch0, int batched) {
  __shared__ unsigned short P_lds[4][2048];  // per-wave P half-tile [64 q][32 k], swizzled
  __shared__ unsigned short y_t[16384];      // [pos 64][c 256] bf16, swizzled

  const int tid = threadIdx.x;
  const int lane = tid & 63;
  const int wid = tid >> 6;
  const int g = lane >> 4;
  const int qh = lane & 15;
  const int bid = blockIdx.x;
  // XCD-chunked swizzle: XCD j owns winl [j*128, +128).
  const int winl = ((bid & 7) << 7) | (bid >> 3);
  const int batch = batch0 + blockIdx.z;
  const size_t qofs = batched ? (size_t)blockIdx.z * QKV_STRIDE : 0;
  const float scale = 0.17677669529663687f;  // 1/sqrt(32)

  char* pbase = (char*)&P_lds[wid][0];

#pragma unroll
  for (int hi = 0; hi < 2; ++hi) {
    const int head = wid + hi * 4;
    const unsigned short* qb = q_w + qofs + (size_t)(winl * 8 + head) * 2048;
    const unsigned short* kb = k_w + qofs + (size_t)(winl * 8 + head) * 2048;
    const unsigned short* vb = v_w + qofs + (size_t)(winl * 8 + head) * 2048;

    bfx8 kf[4], qf[4];
#pragma unroll
    for (int t = 0; t < 4; ++t) {
      kf[t] = *(const bfx8*)(kb + (t * 16 + qh) * 32 + g * 8);
      qf[t] = *(const bfx8*)(qb + (t * 16 + qh) * 32 + g * 8);
    }
    // S^T[kpos][q] = sum_d K[kpos][d] * Q[q][d]
    f32x4 zero = {0.f, 0.f, 0.f, 0.f};
    f32x4 st[4][4];
#pragma unroll
    for (int kt = 0; kt < 4; ++kt)
#pragma unroll
      for (int qt = 0; qt < 4; ++qt)
        st[kt][qt] = __builtin_amdgcn_mfma_f32_16x16x32_bf16(kf[kt], qf[qt], zero, 0, 0, 0);

    // softmax over kpos (rows of S^T)
    float rv[4];
#pragma unroll
    for (int qt = 0; qt < 4; ++qt) {
      float m = -1e30f;
#pragma unroll
      for (int kt = 0; kt < 4; ++kt) {
        f32x4 v = st[kt][qt];
        m = fmaxf(m, fmaxf(fmaxf(v.x, v.y), fmaxf(v.z, v.w)));
      }
      m = fmaxf(m, __shfl_xor(m, 16, 64));
      m = fmaxf(m, __shfl_xor(m, 32, 64));
      float ssum = 0.f;
#pragma unroll
      for (int kt = 0; kt < 4; ++kt) {
        f32x4 v = st[kt][qt], e;
        e.x = __expf((v.x - m) * scale);
        e.y = __expf((v.y - m) * scale);
        e.z = __expf((v.z - m) * scale);
        e.w = __expf((v.w - m) * scale);
        ssum += e.x + e.y + e.z + e.w;
        st[kt][qt] = e;
      }
      ssum += __shfl_xor(ssum, 16, 64);
      ssum += __shfl_xor(ssum, 32, 64);
      rv[qt] = 1.f / ssum;
    }

    // PV: out^T[d][q] = sum_k V^T[d][k] * P
    f32x4 ot[2][4];
#pragma unroll
    for (int dt = 0; dt < 2; ++dt)
#pragma unroll
      for (int qt = 0; qt < 4; ++qt) ot[dt][qt] = zero;

#pragma unroll
    for (int s = 0; s < 2; ++s) {
#pragma unroll
      for (int qt = 0; qt < 4; ++qt) {
        int q = qt * 16 + qh;
        unsigned sw = ((unsigned)(q & 3)) << 4;
        float r = rv[qt];
#pragma unroll
        for (int k2 = 0; k2 < 2; ++k2) {
          f32x4 e = st[s * 2 + k2][qt];
          uint2 pv;
          pv.x = (unsigned)f2bf(e.x * r) | ((unsigned)f2bf(e.y * r) << 16);
          pv.y = (unsigned)f2bf(e.z * r) | ((unsigned)f2bf(e.w * r) << 16);
          unsigned byte = ((unsigned)q * 64 + (unsigned)(k2 * 32 + g * 8)) ^ sw;
          *(uint2*)(pbase + byte) = pv;
        }
      }
      bfx8 pf[4];
#pragma unroll
      for (int qt = 0; qt < 4; ++qt) {
        int q = qt * 16 + qh;
        unsigned byte = ((unsigned)q * 64 + (unsigned)(g * 16)) ^ (((unsigned)(q & 3)) << 4);
        pf[qt] = *(const bfx8*)(pbase + byte);
      }
#pragma unroll
      for (int dt = 0; dt < 2; ++dt) {
        bfx8 vf = *(const bfx8*)(vb + (dt * 16 + qh) * 64 + s * 32 + g * 8);
#pragma unroll
        for (int qt = 0; qt < 4; ++qt)
          ot[dt][qt] = __builtin_amdgcn_mfma_f32_16x16x32_bf16(vf, pf[qt], ot[dt][qt], 0, 0, 0);
      }
    }

    // attention output -> y_t[pos][c] (swizzled), c = head*32 + d
#pragma unroll
    for (int dt = 0; dt < 2; ++dt) {
      int cb = head * 32 + dt * 16 + g * 4;
#pragma unroll
      for (int qt = 0; qt < 4; ++qt) {
        int pos = qt * 16 + qh;
        f32x4 a = ot[dt][qt];
        uint2 pv;
        pv.x = (unsigned)f2bf(a.x) | ((unsigned)f2bf(a.y) << 16);
        pv.y = (unsigned)f2bf(a.z) | ((unsigned)f2bf(a.w) << 16);
        unsigned byte = ((unsigned)pos * 512 + (unsigned)cb * 2) ^ (((unsigned)(pos & 7)) << 4);
        *(uint2*)((char*)y_t + byte) = pv;
      }
    }
  }
  __syncthreads();

  // output conv: out[o][pos] = sum_c wp[o][c] * y[c][pos]; wave wid: o in [64*wid, +64)
  f32x4 acc[4][4];
#pragma unroll
  for (int i = 0; i < 4; ++i)
#pragma unroll
    for (int j = 0; j < 4; ++j) acc[i][j] = (f32x4){0.f, 0.f, 0.f, 0.f};

  for (int ks = 0; ks < 8; ++ks) {
    bfx8 af[4];
#pragma unroll
    for (int mt = 0; mt < 4; ++mt)
      af[mt] = *(const bfx8*)(wpT + (((wid * 4 + mt) * 8 + ks) * 64 + lane) * 8);
#pragma unroll
    for (int nt = 0; nt < 4; ++nt) {
      int pos = nt * 16 + qh;
      unsigned byte = ((unsigned)pos * 512 + (unsigned)(ks * 64 + g * 16)) ^ (((unsigned)(pos & 7)) << 4);
      bfx8 bfr = *(const bfx8*)((char*)y_t + byte);
#pragma unroll
      for (int mt = 0; mt < 4; ++mt)
        acc[mt][nt] = __builtin_amdgcn_mfma_f32_16x16x32_bf16(af[mt], bfr, acc[mt][nt], 0, 0, 0);
    }
  }

  const int wrow = winl >> 5, wcol = winl & 31;
  float* ob_ = out + (size_t)batch * NC * HW;
#pragma unroll
  for (int mt = 0; mt < 4; ++mt) {
    int o0 = wid * 64 + mt * 16 + g * 4;
    float b0 = bp[o0], b1 = bp[o0 + 1], b2 = bp[o0 + 2], b3 = bp[o0 + 3];
#pragma unroll
    for (int nt = 0; nt < 4; ++nt) {
      int pos = nt * 16 + qh;
      int h_img = wrow * 8 + (pos >> 3);
      int w_img = wcol * 8 + (pos & 7);
      float* pp = ob_ + (size_t)o0 * HW + h_img * 256 + w_img;
      pp[0]      = acc[mt][nt].x + b0;
      pp[HW]     = acc[mt][nt].y + b1;
      pp[2 * HW] = acc[mt][nt].z + b2;
      pp[3 * HW] = acc[mt][nt].w + b3;
    }
  }
}

extern "C" void kernel_launch(void* const* d_in, const int* in_sizes, int n_in,
                              void* d_out, int out_size, void* d_ws, size_t ws_size,
                              hipStream_t stream) {
  const float* q_feat = (const float*)d_in[0];
  const float* kv_feat = (const float*)d_in[1];
  const float* wq = (const float*)d_in[2];
  const float* bq = (const float*)d_in[3];
  const float* wk = (const float*)d_in[4];
  const float* bk = (const float*)d_in[5];
  const float* wv = (const float*)d_in[6];
  const float* bv = (const float*)d_in[7];
  const float* wp = (const float*)d_in[8];
  const float* bp = (const float*)d_in[9];
  float* out = (float*)d_out;

  unsigned short* wbf = (unsigned short*)d_ws;  // 4 x 65536 bf16 = 512 KB
  // weights + 4-batch QKV + 8 MB diag scratch
  const size_t need_batched = 524288ul + 12ul * QKV_STRIDE * 2ul + (8ul << 20);

  hipLaunchKernelGGL(prep_weights, dim3(256), dim3(256), 0, stream, wq, wk, wv, wp, wbf);

  if (ws_size >= need_batched) {
    unsigned short* q_w = wbf + 262144;
    unsigned short* k_w = q_w + 4 * QKV_STRIDE;
    unsigned short* v_w = k_w + 4 * QKV_STRIDE;
    float* scratch = (float*)(v_w + 4 * QKV_STRIDE);  // 2 x 2MB

    // diagnostics (batch-0 grid; outputs to scratch only)
    hipLaunchKernelGGL(qkv_stage_diag, dim3(2048), dim3(256), 0, stream,
                       q_feat, kv_feat, scratch);
    hipLaunchKernelGGL(qkv_nostore_diag, dim3(2048), dim3(256), 0, stream,
                       q_feat, kv_feat, wbf, scratch + 524288);

    // real kernels (all batches)
    hipLaunchKernelGGL(qkv_gemm, dim3(2048, 1, 4), dim3(256), 0, stream,
                       q_feat, kv_feat, wbf, bq, bk, bv, q_w, k_w, v_w, 0, 1);
    hipLaunchKernelGGL(attn_conv, dim3(1024, 1, 4), dim3(256), 0, stream,
                       q_w, k_w, v_w, wbf + 196608, bp, out, 0, 1);
  } else {
    // per-batch fallback (~97 MB workspace), no diagnostics
    unsigned short* q_w = wbf + 262144;
    unsigned short* k_w = q_w + QKV_STRIDE;
    unsigned short* v_w = k_w + QKV_STRIDE;
    for (int b = 0; b < 4; ++b) {
      hipLaunchKernelGGL(qkv_gemm, dim3(2048, 1, 1), dim3(256), 0, stream,
                         q_feat, kv_feat, wbf, bq, bk, bv, q_w, k_w, v_w, b, 0);
      hipLaunchKernelGGL(attn_conv, dim3(1024, 1, 1), dim3(256), 0, stream,
                         q_w, k_w, v_w, wbf + 196608, bp, out, b, 0);
    }
  }
}